// Round 12
// baseline (170.394 us; speedup 1.0000x reference)
//
#include <hip/hip_runtime.h>
#include <hip/hip_bf16.h>
#include <math.h>

// H2R detector: score map -> 3x3 NMS peaks -> per-batch top-1000 -> ROIs.
// [B=32,1,512,512] fp32 inputs; out = rois[32,1000,5] ++ scores[32,1000]
// ++ valid[32,1000] = 224000 floats.
//
// Scoring replicates numpy's SIMD (Cephes) fp32 expf op-for-op (verified
// bit-exact rounds 5-11: absmax 0.0). DO NOT alter score or emit paths.
//
// Round 12: fused counting-sorts each strip's peaks by 512 descending score
// classes (class = 2031 - (bits>>19)) and stores per-class u16 counts.
// Select reads counts (32 KB), finds the minimal class cut C* covering K
// (top-K provably within classes <= C*), then copies ONLY the segment
// prefixes (~2k keys) into LDS -- no histogram, no T-scan, no atomics --
// then adaptive bitonic + verified emit. Kills select's two 300 KB streams.

#define B_   32
#define H_   512
#define W_   512
#define HW_  (H_ * W_)
#define K_   1000
#define ROWS_ 16            // interior rows per strip
#define THR_  512           // threads per fused block (8 waves)
#define NSTRIP_ 32          // H_/ROWS_
#define SEGCAP_ 1200        // per-strip peak capacity (mean ~900)
#define NCLS_ 512           // score classes (2 fine-buckets wide)
#define CAND4_ 4096         // candidate LDS capacity

__device__ __forceinline__ int class_of(unsigned int bits) {
    int cls = 2031 - (int)(bits >> 19);   // score<1.0 -> bits>>19 <= 2031
    return cls > (NCLS_ - 1) ? (NCLS_ - 1) : cls;   // cls >= 0 always
}

// ---- numpy SIMD (Cephes) fp32 exp replica — bit-exact, do not touch -------
__device__ __forceinline__ float np_expf(float x) {
#pragma clang fp contract(off)
    const float log2e = 1.44269504088896341f;
    float z = x * log2e;
    float m = rintf(z);
    float r = fmaf(m, -0.693359375f, x);
    r = fmaf(m, 2.12194440e-4f, r);
    float r2 = r * r;
    float p = fmaf(1.9875691500e-4f, r, 1.3981999507e-3f);
    p = fmaf(p, r, 8.3334519073e-3f);
    p = fmaf(p, r, 4.1665795894e-2f);
    p = fmaf(p, r, 1.6666665459e-1f);
    p = fmaf(p, r, 5.0000001201e-1f);
    p = fmaf(p, r2, r);
    p = p + 1.0f;
    int mi = (int)m;
    float sc = __int_as_float((127 + mi) << 23);
    return p * sc;
}

__device__ __forceinline__ float sigmoid_np(float x) {
#pragma clang fp contract(off)
    float e = np_expf(-x);
    float d = 1.0f + e;
    return 1.0f / d;
}

__device__ __forceinline__ float score_ref(float r, float u) {
#pragma clang fp contract(off)
    float s  = sigmoid_np(r);
    float s2 = s * s;
    float su = sigmoid_np(u);
    float t  = 0.35f * su;
    float m  = 1.0f - t;
    return s2 * m;
}

__device__ __forceinline__ float sigmoid_fast(float x) {  // box geometry only
    return 1.0f / (1.0f + __expf(-x));
}

// ---- Fused: score + peak test -> class-sorted segment + class counts ------
__global__ __launch_bounds__(THR_, 4) void fused_peak_kernel(
    const float* __restrict__ route, const float* __restrict__ unc,
    unsigned long long* __restrict__ plist, unsigned short* __restrict__ cnt16)
{
    __shared__ float sm[ROWS_ + 2][W_];          // 36.9 KB
    __shared__ unsigned long long pbuf[SEGCAP_]; // 9.6 KB
    __shared__ unsigned int ccnt[NCLS_];         // 2 KB
    __shared__ unsigned int coff[NCLS_];         // 2 KB
    __shared__ int lcnt;

    const int tid   = threadIdx.x;
    const int lane  = tid & 63;
    const int wid   = tid >> 6;
    const int strip = blockIdx.x;                // 0..31
    const int b     = blockIdx.y;                // 0..31
    const int r0    = strip * ROWS_;
    if (tid == 0) lcnt = 0;
    if (tid < NCLS_) ccnt[tid] = 0u;

    const float4* rb4 = (const float4*)(route + (size_t)b * HW_);
    const float4* ub4 = (const float4*)(unc   + (size_t)b * HW_);
    unsigned long long* seg =
        plist + (size_t)(b * NSTRIP_ + strip) * SEGCAP_;

    // Stage 18 halo rows: branchless (slot clamp), 10 loads in flight.
    float4 rv[5], uv[5];
    int lrow[5], c4[5]; bool ok[5];
    #pragma unroll
    for (int k = 0; k < 5; ++k) {
        int slot = tid + k * THR_;
        slot = slot < 2303 ? slot : 2303;
        int row = slot >> 7;
        int gy  = r0 - 1 + row;
        lrow[k] = row; c4[k] = slot & 127;
        ok[k]   = (gy >= 0 && gy < H_);
        int cy  = gy < 0 ? 0 : (gy >= H_ ? H_ - 1 : gy);
        rv[k] = rb4[cy * 128 + c4[k]];
        uv[k] = ub4[cy * 128 + c4[k]];
    }
    #pragma unroll
    for (int k = 0; k < 5; ++k) {
        float4 s;
        s.x = score_ref(rv[k].x, uv[k].x);
        s.y = score_ref(rv[k].y, uv[k].y);
        s.z = score_ref(rv[k].z, uv[k].z);
        s.w = score_ref(rv[k].w, uv[k].w);
        if (!ok[k]) { s.x = -INFINITY; s.y = -INFINITY;
                      s.z = -INFINITY; s.w = -INFINITY; }
        *(float4*)&sm[lrow[k]][c4[k] * 4] = s;
    }
    __syncthreads();

    // Peak test: 16x512 interior, 4-px groups, float4 reads + column max.
    #pragma unroll
    for (int j = 0; j < 4; ++j) {
        int g  = tid + j * THR_;                 // 0..2047
        int ly = 1 + (g >> 7);                   // 1..16
        int x0 = (g & 127) * 4;
        int gy = r0 + (ly - 1);
        float4 q0 = *(const float4*)&sm[ly - 1][x0];
        float4 q1 = *(const float4*)&sm[ly    ][x0];
        float4 q2 = *(const float4*)&sm[ly + 1][x0];
        bool hasL = (x0 > 0), hasR = (x0 + 4 < W_);
        float l0 = hasL ? sm[ly - 1][x0 - 1] : -INFINITY;
        float l1 = hasL ? sm[ly    ][x0 - 1] : -INFINITY;
        float l2 = hasL ? sm[ly + 1][x0 - 1] : -INFINITY;
        float e0 = hasR ? sm[ly - 1][x0 + 4] : -INFINITY;
        float e1 = hasR ? sm[ly    ][x0 + 4] : -INFINITY;
        float e2 = hasR ? sm[ly + 1][x0 + 4] : -INFINITY;
        float f_m1 = fmaxf(l0, fmaxf(l1, l2));
        float f_0  = fmaxf(q0.x, fmaxf(q1.x, q2.x));
        float f_1  = fmaxf(q0.y, fmaxf(q1.y, q2.y));
        float f_2  = fmaxf(q0.z, fmaxf(q1.z, q2.z));
        float f_3  = fmaxf(q0.w, fmaxf(q1.w, q2.w));
        float f_4  = fmaxf(e0, fmaxf(e1, e2));
        float tb0  = fmaxf(q0.x, q2.x);
        float tb1  = fmaxf(q0.y, q2.y);
        float tb2  = fmaxf(q0.z, q2.z);
        float tb3  = fmaxf(q0.w, q2.w);
        float vv[4] = { q1.x, q1.y, q1.z, q1.w };
        float mm[4];
        mm[0] = fmaxf(fmaxf(f_m1, f_1), tb0);
        mm[1] = fmaxf(fmaxf(f_0,  f_2), tb1);
        mm[2] = fmaxf(fmaxf(f_1,  f_3), tb2);
        mm[3] = fmaxf(fmaxf(f_2,  f_4), tb3);
        #pragma unroll
        for (int i = 0; i < 4; ++i) {
            bool take = (vv[i] >= mm[i]);
            unsigned long long mk = __ballot(take);
            if (mk) {
                int ldr = __ffsll((unsigned long long)mk) - 1;
                int base_ = 0;
                if (lane == ldr) base_ = atomicAdd(&lcnt, __popcll(mk));
                base_ = __shfl(base_, ldr, 64);
                if (take) {
                    int p = base_ + __popcll(mk & ((1ull << lane) - 1ull));
                    unsigned int bits = __float_as_uint(vv[i]);
                    unsigned int idx  = (unsigned int)(gy * W_ + x0 + i);
                    if (p < SEGCAP_)
                        pbuf[p] = ((unsigned long long)bits << 32)
                                  | (0xFFFFFFFFu - idx);
                }
            }
        }
    }
    __syncthreads();
    const int n = lcnt < SEGCAP_ ? lcnt : SEGCAP_;

    // Count classes over stored peaks.
    for (int i = tid; i < n; i += THR_)
        atomicAdd(&ccnt[class_of((unsigned int)(pbuf[i] >> 32))], 1u);
    __syncthreads();

    // Exclusive prefix (class-ascending = score-descending) by wave0.
    if (wid == 0) {
        int carry = 0;
        for (int k = 0; k < NCLS_ / 64; ++k) {
            int c = k * 64 + lane;
            int v = (int)ccnt[c];
            int pre = v;
            #pragma unroll
            for (int off = 1; off < 64; off <<= 1) {
                int o = __shfl_up(pre, off, 64);
                if (lane >= off) pre += o;
            }
            coff[c] = (unsigned int)(carry + pre - v);
            carry += __shfl(pre, 63, 64);
        }
    }
    __syncthreads();

    // Scatter to global segment in class order + store class counts.
    for (int i = tid; i < n; i += THR_) {
        unsigned long long key = pbuf[i];
        int cls = class_of((unsigned int)(key >> 32));
        unsigned int pos = atomicAdd(&coff[cls], 1u);
        seg[pos] = key;
    }
    if (tid < NCLS_)
        cnt16[(size_t)(b * NSTRIP_ + strip) * NCLS_ + tid] =
            (unsigned short)ccnt[tid];
}

// ---- Select: counts -> class cut C* -> prefix copy -> sort -> emit --------
__global__ __launch_bounds__(1024) void select_kernel(
    const float* __restrict__ scale, const float* __restrict__ unc,
    const unsigned long long* __restrict__ plist,
    const unsigned short* __restrict__ cnt16,
    const int* __restrict__ ih_p, const int* __restrict__ iw_p,
    float* __restrict__ out)
{
    // scnt (32 KB) is dead after slen/sbase are computed; cand reuses it.
    __shared__ __align__(16) unsigned char smem[CAND4_ * 8];   // 32 KB
    __shared__ unsigned int tot[NCLS_];                        // 2 KB
    __shared__ int slen[NSTRIP_], sbase[NSTRIP_];
    __shared__ int sh_C, sh_n;

    unsigned int* scnt = (unsigned int*)smem;          // 8192 u32 = [s][cls] u16
    unsigned long long* cand = (unsigned long long*)smem;

    const int b = blockIdx.x, tid = threadIdx.x;
    const int lane = tid & 63, wid = tid >> 6;
    if (tid == 0) { sh_C = NCLS_ - 1; sh_n = 0; }

    // Load this batch's class-count table (32x512 u16 = 32 KB).
    const unsigned int* g =
        (const unsigned int*)(cnt16 + (size_t)b * NSTRIP_ * NCLS_);
    for (int i = tid; i < NSTRIP_ * NCLS_ / 2; i += 1024) scnt[i] = g[i];
    __syncthreads();

    // Per-class totals across strips.
    if (tid < NCLS_) {
        unsigned int s = 0;
        for (int st = 0; st < NSTRIP_; ++st) {
            unsigned int w = scnt[st * (NCLS_ / 2) + (tid >> 1)];
            s += (tid & 1) ? (w >> 16) : (w & 0xFFFFu);
        }
        tot[tid] = s;
    }
    __syncthreads();

    // Wave0: minimal class C* with cumulative count >= K (classes ascend =
    // scores descend). Top-K provably lies within classes <= C*.
    if (wid == 0) {
        int cum = 0;
        for (int k = 0; k < NCLS_ / 64; ++k) {
            int c = k * 64 + lane;
            int v = (int)tot[c];
            int pre = v;
            #pragma unroll
            for (int off = 1; off < 64; off <<= 1) {
                int o = __shfl_up(pre, off, 64);
                if (lane >= off) pre += o;
            }
            int ctot = __shfl(pre, 63, 64);
            if (cum + ctot < K_) { cum += ctot; continue; }
            bool cond = (cum + pre) >= K_;
            unsigned long long mask = __ballot(cond);
            int fs = __ffsll((unsigned long long)mask) - 1;
            if (lane == 0) sh_C = k * 64 + fs;
            break;
        }
    }
    __syncthreads();
    const int Cstar = sh_C;

    // Per-strip prefix lengths (classes 0..C*).
    if (tid < NSTRIP_) {
        int len = 0;
        for (int c = 0; c <= Cstar; ++c) {
            unsigned int w = scnt[tid * (NCLS_ / 2) + (c >> 1)];
            len += (c & 1) ? (int)(w >> 16) : (int)(w & 0xFFFFu);
        }
        slen[tid] = len;
    }
    __syncthreads();
    if (tid == 0) {
        int acc = 0;
        for (int s = 0; s < NSTRIP_; ++s) { sbase[s] = acc; acc += slen[s]; }
        sh_n = acc;
    }
    __syncthreads();
    // scnt is dead from here; cand overwrites smem.

    const int n = sh_n < CAND4_ ? sh_n : CAND4_;
    for (int s = 0; s < NSTRIP_; ++s) {
        int len = slen[s], base = sbase[s];
        const unsigned long long* sg =
            plist + (size_t)(b * NSTRIP_ + s) * SEGCAP_;
        for (int i = tid; i < len; i += 1024)
            if (base + i < CAND4_) cand[base + i] = sg[i];
    }
    __syncthreads();
    int sortN = (n <= 1024) ? 1024 : ((n <= 2048) ? 2048 : CAND4_);
    for (int i = tid; i < sortN; i += 1024)
        if (i >= n) cand[i] = 0ull;

    // Pair-indexed bitonic sort (desc, exact 64-bit key) — verified.
    for (int kk = 2; kk <= sortN; kk <<= 1) {
        for (int jj = kk >> 1; jj > 0; jj >>= 1) {
            __syncthreads();
            for (int p = tid; p < (sortN >> 1); p += 1024) {
                int i   = ((p & ~(jj - 1)) << 1) | (p & (jj - 1));
                int ixj = i | jj;
                bool desc = ((i & kk) == 0);
                unsigned long long a = cand[i], c2 = cand[ixj];
                if (desc ? (a < c2) : (a > c2)) { cand[i] = c2; cand[ixj] = a; }
            }
        }
    }
    __syncthreads();

    // Emit top-K (verified path — do not touch).
    const float fih = (float)(*ih_p);
    const float fiw = (float)(*iw_p);
    float* rois   = out;                       // [B,K,5]
    float* scores = out + (size_t)B_ * K_ * 5; // [B,K]
    float* validf = out + (size_t)B_ * K_ * 6; // [B,K]

    for (int k = tid; k < K_; k += 1024) {
        int o = b * K_ + k;
        unsigned long long key = cand[k];
        unsigned int bits = (unsigned int)(key >> 32);
        if (bits == 0u) {
            rois[o * 5 + 0] = 0.0f; rois[o * 5 + 1] = 0.0f;
            rois[o * 5 + 2] = 0.0f; rois[o * 5 + 3] = 0.0f;
            rois[o * 5 + 4] = 0.0f;
            scores[o] = 0.0f; validf[o] = 0.0f;
        } else {
            float v = __uint_as_float(bits);
            unsigned int idx = 0xFFFFFFFFu - (unsigned int)(key & 0xFFFFFFFFull);
            int y = (int)(idx >> 9), x = (int)(idx & 511u);
            float cx = ((float)x + 0.5f) * 4.0f;
            float cy = ((float)y + 0.5f) * 4.0f;
            float ss = sigmoid_fast(scale[(size_t)b * HW_ + idx]);
            float su = sigmoid_fast(unc  [(size_t)b * HW_ + idx]);
            float side = (32.0f + ss * 480.0f) * (1.0f + 0.25f * su);
            float half = 0.5f * side;
            float x1 = fminf(fmaxf(cx - half, 0.0f), fiw - 1.0f);
            float y1 = fminf(fmaxf(cy - half, 0.0f), fih - 1.0f);
            float x2 = fminf(fmaxf(cx + half, 1.0f), fiw);
            float y2 = fminf(fmaxf(cy + half, 1.0f), fih);
            rois[o * 5 + 0] = (float)b;
            rois[o * 5 + 1] = x1; rois[o * 5 + 2] = y1;
            rois[o * 5 + 3] = x2; rois[o * 5 + 4] = y2;
            scores[o] = v; validf[o] = 1.0f;
        }
    }
}

extern "C" void kernel_launch(void* const* d_in, const int* in_sizes, int n_in,
                              void* d_out, int out_size, void* d_ws, size_t ws_size,
                              hipStream_t stream) {
    const float* route = (const float*)d_in[0];
    const float* scale = (const float*)d_in[1];
    const float* unc   = (const float*)d_in[2];
    const int*   ih    = (const int*)d_in[3];
    const int*   iw    = (const int*)d_in[4];
    float* out = (float*)d_out;

    // ws: [cnt16 32*32*512*2 = 1MB][plist 32*32*1200*8 = 9.83MB].
    // Every byte select reads is freshly written each launch -> no memset.
    unsigned short* cnt16 = (unsigned short*)d_ws;
    unsigned long long* plist =
        (unsigned long long*)((char*)d_ws + (size_t)B_ * NSTRIP_ * NCLS_ * 2);

    dim3 g(NSTRIP_, B_);      // 32 strips x 32 batches
    fused_peak_kernel<<<g, THR_, 0, stream>>>(route, unc, plist, cnt16);
    select_kernel<<<B_, 1024, 0, stream>>>(scale, unc, plist, cnt16,
                                           ih, iw, out);
}